// Round 11
// baseline (973.975 us; speedup 1.0000x reference)
//
#include <hip/hip_runtime.h>
#include <hip/hip_bf16.h>
#include <math.h>

// ---------------------------------------------------------------------------
// DeepSeekV3 MLA forward, bf16 MFMA pipeline.  Workspace: 237.0 MB (overlaid).
// B=2, S=2048, H=32, DN=128, DR=64, DV=128, HID=4096, QR=1536, KVR=512
// Fusions: q_a+kv_a+k_rope in one 4096^3 GEMM; q_b GEMM writes Qa layout;
// kv_b GEMM splits k_nope->Ka / V->compact; RoPE touches rope dims only.
// Attention: producer/consumer wave specialization (4 QK/softmax + 4 PV waves).
// ---------------------------------------------------------------------------

typedef __attribute__((ext_vector_type(8))) short s16x8;   // 8 x bf16 (4 VGPR)
typedef __attribute__((ext_vector_type(4))) float f32x4;
typedef __attribute__((ext_vector_type(4))) unsigned short u16x4;

#define DEV __device__ __forceinline__

constexpr int Bc = 2, Sc = 2048, Tc = Bc * Sc;     // tokens = 4096
constexpr int Hc = 32, DNc = 128, DRc = 64, DVc = 128;
constexpr int HIDc = 4096, QRc = 1536, KVRc = 512;
constexpr int DQK = DNc + DRc;                      // 192

DEV unsigned short f2bf(float f) {
  unsigned u = __float_as_uint(f);
  return (unsigned short)((u + 0x7fffu + ((u >> 16) & 1u)) >> 16);
}
DEV float bf2f(unsigned short u) { return __uint_as_float(((unsigned)u) << 16); }

DEV void gll16(const void* g, void* l) {
  __builtin_amdgcn_global_load_lds((const __attribute__((address_space(1))) void*)g,
                                   (__attribute__((address_space(3))) void*)l, 16, 0, 0);
}
DEV f32x4 mfma_bf16(s16x8 a, s16x8 b, f32x4 c) {
  return __builtin_amdgcn_mfma_f32_16x16x32_bf16(a, b, c, 0, 0, 0);
}
DEV unsigned cvt_pk_bf16(float a, float b) {     // lo=bf16(a), hi=bf16(b)
  unsigned r;
  asm("v_cvt_pk_bf16_f32 %0, %1, %2" : "=v"(r) : "v"(a), "v"(b));
  return r;
}

// ---------------------------------------------------------------------------
// cast fp32 -> bf16, 4 elems/thread
// ---------------------------------------------------------------------------
__global__ __launch_bounds__(256) void cast_k(const float* __restrict__ in,
                                              unsigned short* __restrict__ out, long n) {
  long i = ((long)blockIdx.x * 256 + threadIdx.x) * 4;
  if (i >= n) return;
  float4 v = *(const float4*)(in + i);
  u16x4 o;
  o.x = f2bf(v.x); o.y = f2bf(v.y); o.z = f2bf(v.z); o.w = f2bf(v.w);
  *(u16x4*)(out + i) = o;
}

// ---------------------------------------------------------------------------
// RMSNorm, in-place on bf16 columns [0,COLS) of a pitched row, 1 block/row
// ---------------------------------------------------------------------------
template <int COLS>
__global__ __launch_bounds__(256) void rmsnorm_bf_k(unsigned short* __restrict__ x,
                                                    const float* __restrict__ w,
                                                    int pitch) {
  const int row = blockIdx.x;
  unsigned short* p = x + (size_t)row * pitch;
  float ss = 0.f;
  for (int c = threadIdx.x * 8; c < COLS; c += 2048) {
    s16x8 v = *(const s16x8*)&p[c];
    #pragma unroll
    for (int j = 0; j < 8; ++j) { const float f = bf2f((unsigned short)v[j]); ss += f * f; }
  }
  #pragma unroll
  for (int off = 1; off < 64; off <<= 1) ss += __shfl_xor(ss, off, 64);
  __shared__ float sred[4];
  if ((threadIdx.x & 63) == 0) sred[threadIdx.x >> 6] = ss;
  __syncthreads();
  const float inv = rsqrtf((sred[0] + sred[1] + sred[2] + sred[3]) / (float)COLS + 1e-6f);
  for (int c = threadIdx.x * 8; c < COLS; c += 2048) {
    s16x8 v = *(const s16x8*)&p[c];
    s16x8 o;
    #pragma unroll
    for (int j = 0; j < 8; ++j)
      o[j] = (short)f2bf(bf2f((unsigned short)v[j]) * inv * w[c + j]);
    *(s16x8*)&p[c] = o;
  }
}

// ---------------------------------------------------------------------------
// GEMM: C[M,N] = A[M,K](bf16, row pitch lda) * B[N,K]^T(bf16, pitch K).
// 256x256 tile, BK=64.  512 thr = 8 waves (2M x 4N), 128x64 out per wave.
// Counted vmcnt(8) double-buffer; 4 quadrant phases with setprio (m201).
// LDS swizzle via pre-swizzled gll16 SOURCE (linear dest), XOR (row&7)<<3.
// MODE: 0 = bf16 linear, 1 = f32 linear,
//       2 = Qa layout   (row=token, col=h*192+d  -> Qa[bh][s][192])
//       3 = kv split    (col=h*256+c: c<128 -> Ka[bh][s][192]; else V compact)
// ---------------------------------------------------------------------------
template <int MODE>
__global__ __launch_bounds__(512, 2) void gemm256_bt(const unsigned short* __restrict__ A,
                                                     int lda,
                                                     const unsigned short* __restrict__ B,
                                                     void* __restrict__ Cout,
                                                     void* __restrict__ Cout2,
                                                     int M, int N, int K) {
  __shared__ unsigned short As[2][256 * 64];    // 64 KB
  __shared__ unsigned short Bs[2][256 * 64];    // 64 KB
  const int tid = threadIdx.x;
  const int wv = tid >> 6, l = tid & 63;
  const int lo = l & 15, hi = l >> 4;
  const int wm = wv >> 2, wn = wv & 3;          // wave grid 2 x 4
  // bijective XCD swizzle (m204)
  const int nbx = N >> 8;
  const int nwg = (M >> 8) * nbx;
  const int orig = blockIdx.x;
  const int q8 = nwg >> 3, r8 = nwg & 7, xc = orig & 7, o8 = orig >> 3;
  const int wg = (xc < r8 ? xc * (q8 + 1) : r8 * (q8 + 1) + (xc - r8) * q8) + o8;
  const int bx = wg % nbx, by = wg / nbx;
  const int m0 = by * 256, n0 = bx * 256;
  const int lrow = l >> 3;                       // row within 8-row gll16 group
  const int lcol = (((l & 7) ^ lrow) << 3);      // pre-swizzled source col (elems)

  f32x4 acc[8][4] = {};
  const int NKT = K >> 6;

  auto stage = [&](int bi, int kt) {
    #pragma unroll
    for (int i = 0; i < 4; ++i) {               // A: rows [wv*32, wv*32+32)
      const int r0 = wv * 32 + i * 8;
      gll16(A + (size_t)(m0 + r0 + lrow) * lda + kt + lcol, (void*)&As[bi][r0 * 64]);
    }
    #pragma unroll
    for (int i = 0; i < 4; ++i) {               // B: rows [wv*32, wv*32+32)
      const int r0 = wv * 32 + i * 8;
      gll16(B + (size_t)(n0 + r0 + lrow) * K + kt + lcol, (void*)&Bs[bi][r0 * 64]);
    }
  };

  stage(0, 0);

  for (int t = 0; t < NKT; ++t) {
    const int bi = t & 1;
    if (t + 1 < NKT) stage(bi ^ 1, (t + 1) * 64);
    __builtin_amdgcn_sched_barrier(0);
    if (t + 1 < NKT) asm volatile("s_waitcnt vmcnt(8)" ::: "memory");
    else             asm volatile("s_waitcnt vmcnt(0)" ::: "memory");
    __builtin_amdgcn_s_barrier();
    __builtin_amdgcn_sched_barrier(0);

    const unsigned short* Ab = As[bi];
    const unsigned short* Bb = Bs[bi];
    auto rdA = [&](int m, int kk) -> s16x8 {
      const int row = wm * 128 + m * 16 + lo;
      return *(const s16x8*)&Ab[row * 64 + ((kk * 32 + hi * 8) ^ ((row & 7) << 3))];
    };
    auto rdB = [&](int n, int kk) -> s16x8 {
      const int row = wn * 64 + n * 16 + lo;
      return *(const s16x8*)&Bb[row * 64 + ((kk * 32 + hi * 8) ^ ((row & 7) << 3))];
    };

    s16x8 a[4][2], b0[2][2], b2[2][2];
    // ---- phase 1: A rows 0-3 + B cols 0-1, quadrant (0,0)
    #pragma unroll
    for (int m = 0; m < 4; ++m) { a[m][0] = rdA(m, 0); a[m][1] = rdA(m, 1); }
    #pragma unroll
    for (int n = 0; n < 2; ++n) { b0[n][0] = rdB(n, 0); b0[n][1] = rdB(n, 1); }
    __builtin_amdgcn_sched_barrier(0);
    __builtin_amdgcn_s_setprio(1);
    #pragma unroll
    for (int m = 0; m < 4; ++m)
      #pragma unroll
      for (int n = 0; n < 2; ++n) {
        acc[m][n] = mfma_bf16(a[m][0], b0[n][0], acc[m][n]);
        acc[m][n] = mfma_bf16(a[m][1], b0[n][1], acc[m][n]);
      }
    __builtin_amdgcn_s_setprio(0);
    __builtin_amdgcn_sched_barrier(0);
    __builtin_amdgcn_s_barrier();
    // ---- phase 2: B cols 2-3 new, quadrant (0,1)
    #pragma unroll
    for (int n = 0; n < 2; ++n) { b2[n][0] = rdB(n + 2, 0); b2[n][1] = rdB(n + 2, 1); }
    __builtin_amdgcn_sched_barrier(0);
    __builtin_amdgcn_s_setprio(1);
    #pragma unroll
    for (int m = 0; m < 4; ++m)
      #pragma unroll
      for (int n = 0; n < 2; ++n) {
        acc[m][n + 2] = mfma_bf16(a[m][0], b2[n][0], acc[m][n + 2]);
        acc[m][n + 2] = mfma_bf16(a[m][1], b2[n][1], acc[m][n + 2]);
      }
    __builtin_amdgcn_s_setprio(0);
    __builtin_amdgcn_sched_barrier(0);
    __builtin_amdgcn_s_barrier();
    // ---- phase 3: A rows 4-7 new, quadrant (1,1)
    #pragma unroll
    for (int m = 0; m < 4; ++m) { a[m][0] = rdA(m + 4, 0); a[m][1] = rdA(m + 4, 1); }
    __builtin_amdgcn_sched_barrier(0);
    __builtin_amdgcn_s_setprio(1);
    #pragma unroll
    for (int m = 0; m < 4; ++m)
      #pragma unroll
      for (int n = 0; n < 2; ++n) {
        acc[m + 4][n + 2] = mfma_bf16(a[m][0], b2[n][0], acc[m + 4][n + 2]);
        acc[m + 4][n + 2] = mfma_bf16(a[m][1], b2[n][1], acc[m + 4][n + 2]);
      }
    __builtin_amdgcn_s_setprio(0);
    __builtin_amdgcn_sched_barrier(0);
    __builtin_amdgcn_s_barrier();
    // ---- phase 4: all-reuse, quadrant (1,0); end barrier = WAR guard
    __builtin_amdgcn_s_setprio(1);
    #pragma unroll
    for (int m = 0; m < 4; ++m)
      #pragma unroll
      for (int n = 0; n < 2; ++n) {
        acc[m + 4][n] = mfma_bf16(a[m][0], b0[n][0], acc[m + 4][n]);
        acc[m + 4][n] = mfma_bf16(a[m][1], b0[n][1], acc[m + 4][n]);
      }
    __builtin_amdgcn_s_setprio(0);
    __builtin_amdgcn_sched_barrier(0);
    __builtin_amdgcn_s_barrier();
  }

  #pragma unroll
  for (int m = 0; m < 8; ++m)
    #pragma unroll
    for (int n = 0; n < 4; ++n)
      #pragma unroll
      for (int r = 0; r < 4; ++r) {
        const int row = m0 + wm * 128 + m * 16 + hi * 4 + r;   // token for MODE 2/3
        const int col = n0 + wn * 64 + n * 16 + lo;
        const float v = acc[m][n][r];
        if (MODE == 1) {
          ((float*)Cout)[(size_t)row * N + col] = v;
        } else if (MODE == 0) {
          ((unsigned short*)Cout)[(size_t)row * N + col] = f2bf(v);
        } else if (MODE == 2) {
          const int hh = col / DQK, dd = col % DQK;
          const int bb = row >> 11, ss = row & 2047;
          ((unsigned short*)Cout)[((size_t)((bb * Hc + hh) * Sc + ss)) * DQK + dd] = f2bf(v);
        } else {  // MODE 3
          const int hh = col >> 8, cc = col & 255;
          const int bb = row >> 11, ss = row & 2047;
          if (cc < 128)
            ((unsigned short*)Cout)[((size_t)((bb * Hc + hh) * Sc + ss)) * DQK + cc] = f2bf(v);
          else
            ((unsigned short*)Cout2)[(size_t)row * (Hc * DVc) + hh * DVc + (cc - 128)] = f2bf(v);
        }
      }
}

// ---------------------------------------------------------------------------
// RoPE, rope-dims only.  Each thread owns an 8-wide (j, j+32) PAIR.
// ---------------------------------------------------------------------------
DEV void rope_pair8(float pos, int j0, const s16x8& x1, const s16x8& x2,
                    s16x8& o1, s16x8& o2) {
  #pragma unroll
  for (int j = 0; j < 8; ++j) {
    const int jj = j0 + j;                       // 0..31
    const float inv = exp2f(-(float)jj * 0.4152410118f);  // 10000^(-jj/32)
    float sn, cs;
    sincosf(pos * inv, &sn, &cs);
    const float a = bf2f((unsigned short)x1[j]);
    const float c = bf2f((unsigned short)x2[j]);
    o1[j] = f2bf(a * cs - c * sn);
    o2[j] = f2bf(c * cs + a * sn);
  }
}

__global__ __launch_bounds__(256) void rope_q_k(unsigned short* __restrict__ Qa,
                                                const int* __restrict__ pos) {
  const int gid = blockIdx.x * 256 + threadIdx.x;   // Bc*Hc*Sc*4
  const int pr = gid & 3, rowp = gid >> 2;          // rowp = bh*2048+s
  const int j0 = pr * 8;
  const int bh = rowp >> 11, s = rowp & 2047;
  const int token = (bh >> 5) * Sc + s;
  unsigned short* base = Qa + (size_t)rowp * DQK + 128;
  s16x8 x1 = *(const s16x8*)&base[j0];
  s16x8 x2 = *(const s16x8*)&base[j0 + 32];
  s16x8 o1, o2;
  rope_pair8((float)pos[token], j0, x1, x2, o1, o2);
  *(s16x8*)&base[j0] = o1;
  *(s16x8*)&base[j0 + 32] = o2;
}

__global__ __launch_bounds__(256) void rope_k2_k(const unsigned short* __restrict__ kr,
                                                 const int* __restrict__ pos,
                                                 unsigned short* __restrict__ Ka) {
  const int gid = blockIdx.x * 256 + threadIdx.x;
  const int pr = gid & 3, rowp = gid >> 2;
  const int j0 = pr * 8;
  const int bh = rowp >> 11, s = rowp & 2047;
  const int h = bh & 31;
  const int token = (bh >> 5) * Sc + s;
  const unsigned short* src = kr + (size_t)token * HIDc + h * DRc;   // pitch HIDc
  s16x8 x1 = *(const s16x8*)&src[j0];
  s16x8 x2 = *(const s16x8*)&src[j0 + 32];
  s16x8 o1, o2;
  rope_pair8((float)pos[token], j0, x1, x2, o1, o2);
  unsigned short* dst = Ka + (size_t)rowp * DQK + 128;
  *(s16x8*)&dst[j0] = o1;
  *(s16x8*)&dst[j0 + 32] = o2;
}

// ---------------------------------------------------------------------------
// Flash attention, producer/consumer wave specialization.
// 512 thr: waves 0-3 = producers (QK^T swapped + in-register softmax, publish
// P/alpha to LDS), waves 4-7 = consumers (alpha-rescale + PV + O-write),
// pipelined one tile apart.  Block = 128 q-rows (wave pair pw owns 32 rows).
// LDS 113.5 KB: Ks dbuf 48K (gll16, pre-swizzled src), Vs dbuf 32K (consumer
// reg-staged), Ps dbuf 32K + Al dbuf 1K + Li 0.5K (handoff).  All cross-role
// buffers double-buffered; one vmcnt(0)/lgkm(0)+s_barrier per iteration.
// ---------------------------------------------------------------------------
__global__ __launch_bounds__(512, 2) void attn_k(const unsigned short* __restrict__ Q,
                                                 const unsigned short* __restrict__ Kt,
                                                 const unsigned short* __restrict__ KV,
                                                 unsigned short* __restrict__ O) {
  __shared__ unsigned short Ks[2][64 * 192];    // 48 KB
  __shared__ unsigned short Vs[2][128 * 64];    // 32 KB, V^T [dv][key] swizzled
  __shared__ unsigned short Ps[2][4][32 * 64];  // 32 KB, per-producer P, pitch 64
  __shared__ float Al[2][128];                  // 1 KB, per-tile alpha per q-row
  __shared__ float Li[128];                     // 0.5 KB, final l per q-row
  const int bh = blockIdx.x, qblk = blockIdx.y; // bh fastest: same-bh -> same XCD
  const int b = bh >> 5, h = bh & 31;
  const int tid = threadIdx.x, w = tid >> 6, l = tid & 63;
  const int pw = w & 3;
  const int lo = l & 15, hi = l >> 4;
  const int sw = (lo & 7) << 3;
  const unsigned short* Qb = Q + (size_t)bh * Sc * DQK;
  const unsigned short* Kb = Kt + (size_t)bh * Sc * DQK;
  const int qrow0 = qblk * 128 + pw * 32;
  const float c2 = 0.10411759f;                 // (1/sqrt(192)) * log2(e)
  constexpr int NT = Sc / 64;                   // 32

  s16x8 qfr[2][6];                              // producer only
  float mrow[2] = {-INFINITY, -INFINITY};
  float lrow[2] = {0.f, 0.f};
  f32x4 oacc[2][8] = {};                        // consumer only
  s16x8 vv[4];                                  // consumer only

  auto stageK = [&](int kb, int kt) {           // 4 producer waves cover 24 KB
    #pragma unroll
    for (int i = 0; i < 6; ++i) {
      const int o = (pw * 6 + i) * 1024 + l * 16;   // byte offset in 64x192 tile
      const int rr = o / 384, cc = o % 384;
      const int scc = cc ^ ((rr & 7) << 4);
      gll16(Kb + (size_t)(kt + rr) * DQK + (scc >> 1), (void*)&Ks[kb][(pw * 6 + i) * 512]);
    }
  };
  auto loadV = [&](int kt) {                    // 4 consumer waves cover dv 0..127
    #pragma unroll
    for (int itc = 0; itc < 4; ++itc)
      vv[itc] = *(const s16x8*)(KV + (size_t)(b * Sc + kt + l) * (Hc * DVc) + h * DVc +
                                (pw * 4 + itc) * 8);
  };
  auto writeV = [&](int vb) {
    #pragma unroll
    for (int itc = 0; itc < 4; ++itc) {
      const int dv0 = (pw * 4 + itc) * 8;
      #pragma unroll
      for (int j = 0; j < 8; ++j) {
        const int dv = dv0 + j;
        Vs[vb][(dv * 64 + l) ^ ((dv & 7) << 3)] = (unsigned short)vv[itc][j];
      }
    }
  };

  // ---- prologue
  if (w < 4) {
    #pragma unroll
    for (int qf = 0; qf < 2; ++qf)
      #pragma unroll
      for (int dc = 0; dc < 6; ++dc)
        qfr[qf][dc] = *(const s16x8*)&Qb[(size_t)(qrow0 + qf * 16 + lo) * DQK + dc * 32 + hi * 8];
    stageK(0, 0);
  } else {
    loadV(0);
  }
  asm volatile("s_waitcnt vmcnt(0) lgkmcnt(0)" ::: "memory");
  __builtin_amdgcn_s_barrier();
  __builtin_amdgcn_sched_barrier(0);

  for (int it = 0; it <= NT; ++it) {
    if (w < 4) {
      // =============== PRODUCER: tile it ===============
      if (it < NT) {
        if (it + 1 < NT) stageK((it + 1) & 1, (it + 1) * 64);
        __builtin_amdgcn_sched_barrier(0);
        f32x4 sc[2][4] = {};
        const unsigned short* Kc = Ks[it & 1];
        #pragma unroll
        for (int cf = 0; cf < 4; ++cf) {
          const int krow = cf * 16 + lo;
          #pragma unroll
          for (int dc = 0; dc < 6; ++dc) {
            s16x8 kf = *(const s16x8*)&Kc[(krow * 192 + dc * 32 + hi * 8) ^ ((krow & 7) << 3)];
            sc[0][cf] = mfma_bf16(kf, qfr[0][dc], sc[0][cf]);
            sc[1][cf] = mfma_bf16(kf, qfr[1][dc], sc[1][cf]);
          }
        }
        #pragma unroll
        for (int qf = 0; qf < 2; ++qf) {
          float mx = sc[qf][0][0];
          #pragma unroll
          for (int cf = 0; cf < 4; ++cf)
            #pragma unroll
            for (int r = 0; r < 4; ++r) mx = fmaxf(mx, sc[qf][cf][r]);
          mx = fmaxf(mx, __shfl_xor(mx, 16, 64));
          mx = fmaxf(mx, __shfl_xor(mx, 32, 64));
          const float nm = fmaxf(mrow[qf], mx * c2);
          const float alpha = exp2f(mrow[qf] - nm);
          mrow[qf] = nm;
          if (hi == 0) Al[it & 1][pw * 32 + qf * 16 + lo] = alpha;
          float psum = 0.f;
          const int qrow = qf * 16 + lo;
          #pragma unroll
          for (int cf = 0; cf < 4; ++cf) {
            float p0 = exp2f(fmaf(sc[qf][cf][0], c2, -nm));
            float p1 = exp2f(fmaf(sc[qf][cf][1], c2, -nm));
            float p2 = exp2f(fmaf(sc[qf][cf][2], c2, -nm));
            float p3 = exp2f(fmaf(sc[qf][cf][3], c2, -nm));
            psum += (p0 + p1) + (p2 + p3);
            const int ka = cf * 16 + hi * 4;
            *(unsigned*)&Ps[it & 1][pw][qrow * 64 + ((ka + 0) ^ sw)] = cvt_pk_bf16(p0, p1);
            *(unsigned*)&Ps[it & 1][pw][qrow * 64 + ((ka + 2) ^ sw)] = cvt_pk_bf16(p2, p3);
          }
          psum += __shfl_xor(psum, 16, 64);
          psum += __shfl_xor(psum, 32, 64);
          lrow[qf] = lrow[qf] * alpha + psum;
        }
      } else {
        // publish final l (consumers read after the loop's last barrier)
        if (hi == 0) {
          Li[pw * 32 + lo] = lrow[0];
          Li[pw * 32 + 16 + lo] = lrow[1];
        }
      }
    } else {
      // =============== CONSUMER: tile it-1 ===============
      if (it < NT) {
        writeV(it & 1);                          // vv holds V(tile it)
        if (it + 1 < NT) loadV((it + 1) * 64);   // prefetch V(tile it+1)
      }
      if (it > 0) {
        const int j = (it - 1) & 1;
        #pragma unroll
        for (int qf = 0; qf < 2; ++qf)
          #pragma unroll
          for (int r = 0; r < 4; ++r) {
            const float ar = Al[j][pw * 32 + qf * 16 + hi * 4 + r];
            #pragma unroll
            for (int dvf = 0; dvf < 8; ++dvf) oacc[qf][dvf][r] *= ar;
          }
        #pragma unroll
        for (int hf = 0; hf < 2; ++hf) {
          s16x8 pa0 = *(const s16x8*)&Ps[j][pw][lo * 64 + ((hf * 32 + hi * 8) ^ sw)];
          s16x8 pa1 = *(const s16x8*)&Ps[j][pw][(16 + lo) * 64 + ((hf * 32 + hi * 8) ^ sw)];
          #pragma unroll
          for (int dvf = 0; dvf < 8; ++dvf) {
            const int dv = dvf * 16 + lo;
            s16x8 vb = *(const s16x8*)&Vs[j][(dv * 64 + hf * 32 + hi * 8) ^ ((dv & 7) << 3)];
            oacc[0][dvf] = mfma_bf16(pa0, vb, oacc[0][dvf]);
            oacc[1][dvf] = mfma_bf16(pa1, vb, oacc[1][dvf]);
          }
        }
      }
    }
    asm volatile("s_waitcnt vmcnt(0) lgkmcnt(0)" ::: "memory");
    __builtin_amdgcn_s_barrier();
    __builtin_amdgcn_sched_barrier(0);
  }

  // ---- epilogue: consumers write O
  if (w >= 4) {
    #pragma unroll
    for (int qf = 0; qf < 2; ++qf)
      #pragma unroll
      for (int r = 0; r < 4; ++r) {
        const float linv = 1.f / Li[pw * 32 + qf * 16 + hi * 4 + r];
        const int q = qrow0 + qf * 16 + hi * 4 + r;
        #pragma unroll
        for (int dvf = 0; dvf < 8; ++dvf)
          O[(size_t)(b * Sc + q) * (Hc * DVc) + h * DVc + dvf * 16 + lo] =
              f2bf(oacc[qf][dvf][r] * linv);
      }
  }
}

// ---------------------------------------------------------------------------
extern "C" void kernel_launch(void* const* d_in, const int* in_sizes, int n_in,
                              void* d_out, int out_size, void* d_ws, size_t ws_size,
                              hipStream_t stream) {
  const float* hs      = (const float*)d_in[0];
  const int*   posids  = (const int*)d_in[1];
  const float* qa_w    = (const float*)d_in[2];
  const float* qa_ln   = (const float*)d_in[3];
  const float* qb_w    = (const float*)d_in[4];
  const float* kva_w   = (const float*)d_in[5];
  const float* kva_ln  = (const float*)d_in[6];
  const float* kvb_w   = (const float*)d_in[7];
  const float* kr_w    = (const float*)d_in[8];
  const float* o_w     = (const float*)d_in[9];
  float* out = (float*)d_out;

  // ---- overlaid workspace (total 236,978,176 B = 237.0 MB, same as proven) ----
  char* ws = (char*)d_ws;
  const size_t offF = 0;                    // 33,554,432: hs_bf -> w_qb -> w_kvb -> attn_o
  const size_t offR = offF + 33554432;      // 35,651,584: cbuf (33.5M used)
  const size_t offD = offR + 35651584;      // 50,331,648: Ka
  const size_t offA = offD + 50331648;      // 67,108,864: kv_v (33.5M used)
  const size_t offB = offA + 67108864;      // 50,331,648: cw -> Qa -> w_o

  unsigned short* hs_bf  = (unsigned short*)(ws + offF);
  unsigned short* w_qb   = (unsigned short*)(ws + offF);   // after fused gemm
  unsigned short* w_kvb  = (unsigned short*)(ws + offF);   // after q_b gemm
  unsigned short* attn_o = (unsigned short*)(ws + offF);   // after kv_b gemm (pre-attn)
  unsigned short* cbuf   = (unsigned short*)(ws + offR);   // [qa_n | kva_n | kr], pitch 4096
  unsigned short* Ka     = (unsigned short*)(ws + offD);   // direct from kv_b + rope_k2
  unsigned short* kv_v   = (unsigned short*)(ws + offA);   // V compact [token][h*128+dv]
  unsigned short* cw     = (unsigned short*)(ws + offB);   // fused weights [4096][4096]
  unsigned short* Qa     = (unsigned short*)(ws + offB);   // direct from q_b gemm
  unsigned short* w_o    = (unsigned short*)(ws + offB);   // after attn

  auto cast = [&](const float* src, unsigned short* dst, long n) {
    cast_k<<<dim3((unsigned)((n / 4 + 255) / 256)), dim3(256), 0, stream>>>(src, dst, n);
  };

  // 1. hidden states -> bf16
  cast(hs, hs_bf, (long)Tc * HIDc);

  // 2. fused a-projection weights: [qa(1536) | kva(512) | kr(2048)] x 4096
  cast(qa_w,  cw,                              (long)QRc * HIDc);
  cast(kva_w, cw + (size_t)QRc * HIDc,         (long)KVRc * HIDc);
  cast(kr_w,  cw + (size_t)(QRc + KVRc) * HIDc,(long)Hc * DRc * HIDc);

  // 3. fused a-projection GEMM: cbuf[4096][4096] = hs_bf x cw^T  (256 blocks)
  gemm256_bt<0><<<dim3(16 * 16), dim3(512), 0, stream>>>(hs_bf, HIDc, cw,
                                                         (void*)cbuf, nullptr,
                                                         Tc, HIDc, HIDc);

  // 4. RMSNorms in place on pitched columns
  rmsnorm_bf_k<QRc><<<dim3(Tc), dim3(256), 0, stream>>>(cbuf, qa_ln, HIDc);
  rmsnorm_bf_k<KVRc><<<dim3(Tc), dim3(256), 0, stream>>>(cbuf + QRc, kva_ln, HIDc);

  // 5. q_b proj -> Qa layout directly (overwrites cw; cw dead after step 3)
  cast(qb_w, w_qb, (long)Hc * DQK * QRc);
  gemm256_bt<2><<<dim3(16 * 24), dim3(512), 0, stream>>>(cbuf, HIDc, w_qb,
                                                         (void*)Qa, nullptr,
                                                         Tc, Hc * DQK, QRc);

  // 6. kv_b proj -> k_nope into Ka, V into compact kv_v
  cast(kvb_w, w_kvb, (long)Hc * 256 * KVRc);
  gemm256_bt<3><<<dim3(16 * 32), dim3(512), 0, stream>>>(cbuf + QRc, HIDc, w_kvb,
                                                         (void*)Ka, (void*)kv_v,
                                                         Tc, Hc * 256, KVRc);

  // 7. RoPE on rope dims only (pairs, race-free); Qa in-place, Ka from cbuf kr
  const int npair = Bc * Hc * Sc * 4;   // 524,288
  rope_q_k<<<dim3(npair / 256), dim3(256), 0, stream>>>(Qa, posids);
  rope_k2_k<<<dim3(npair / 256), dim3(256), 0, stream>>>(cbuf + QRc + KVRc, posids, Ka);

  // 8. attention: 128 q-rows/block, grid (64 bh, 16 qblk); bh fastest for XCD/L2
  attn_k<<<dim3(Bc * Hc, Sc / 128), dim3(512), 0, stream>>>(Qa, Ka, kv_v, attn_o);

  // 9. output projection -> fp32 d_out (w_o cast into Qa region, dead after attn)
  cast(o_w, w_o, (long)HIDc * Hc * DVc);
  gemm256_bt<1><<<dim3(16 * 16), dim3(512), 0, stream>>>(attn_o, Hc * DVc, w_o,
                                                         (void*)out, nullptr,
                                                         Tc, HIDc, Hc * DVc);

  (void)in_sizes; (void)n_in; (void)out_size; (void)ws_size;
}

// Round 12
// 761.054 us; speedup vs baseline: 1.2798x; 1.2798x over previous
//
#include <hip/hip_runtime.h>
#include <hip/hip_bf16.h>
#include <math.h>

// ---------------------------------------------------------------------------
// DeepSeekV3 MLA forward, bf16 MFMA pipeline.  Workspace: 237.0 MB (overlaid).
// B=2, S=2048, H=32, DN=128, DR=64, DV=128, HID=4096, QR=1536, KVR=512
// Fusions: q_a+kv_a+k_rope in one 4096^3 GEMM; q_b GEMM writes Qa layout;
// kv_b GEMM splits k_nope->Ka / V^T->global [bh][dv][s]; RoPE rope-dims only.
// Attention: 16 q-rows/wave, 56 KB LDS, single-buffered K/V via gll16 ->
// 2 independent blocks/CU (wave-level overlap hides the staging drains).
// ---------------------------------------------------------------------------

typedef __attribute__((ext_vector_type(8))) short s16x8;   // 8 x bf16 (4 VGPR)
typedef __attribute__((ext_vector_type(4))) float f32x4;
typedef __attribute__((ext_vector_type(4))) unsigned short u16x4;

#define DEV __device__ __forceinline__

constexpr int Bc = 2, Sc = 2048, Tc = Bc * Sc;     // tokens = 4096
constexpr int Hc = 32, DNc = 128, DRc = 64, DVc = 128;
constexpr int HIDc = 4096, QRc = 1536, KVRc = 512;
constexpr int DQK = DNc + DRc;                      // 192

DEV unsigned short f2bf(float f) {
  unsigned u = __float_as_uint(f);
  return (unsigned short)((u + 0x7fffu + ((u >> 16) & 1u)) >> 16);
}
DEV float bf2f(unsigned short u) { return __uint_as_float(((unsigned)u) << 16); }

DEV void gll16(const void* g, void* l) {
  __builtin_amdgcn_global_load_lds((const __attribute__((address_space(1))) void*)g,
                                   (__attribute__((address_space(3))) void*)l, 16, 0, 0);
}
DEV f32x4 mfma_bf16(s16x8 a, s16x8 b, f32x4 c) {
  return __builtin_amdgcn_mfma_f32_16x16x32_bf16(a, b, c, 0, 0, 0);
}
DEV unsigned cvt_pk_bf16(float a, float b) {     // lo=bf16(a), hi=bf16(b)
  unsigned r;
  asm("v_cvt_pk_bf16_f32 %0, %1, %2" : "=v"(r) : "v"(a), "v"(b));
  return r;
}

// ---------------------------------------------------------------------------
// cast fp32 -> bf16, 4 elems/thread
// ---------------------------------------------------------------------------
__global__ __launch_bounds__(256) void cast_k(const float* __restrict__ in,
                                              unsigned short* __restrict__ out, long n) {
  long i = ((long)blockIdx.x * 256 + threadIdx.x) * 4;
  if (i >= n) return;
  float4 v = *(const float4*)(in + i);
  u16x4 o;
  o.x = f2bf(v.x); o.y = f2bf(v.y); o.z = f2bf(v.z); o.w = f2bf(v.w);
  *(u16x4*)(out + i) = o;
}

// ---------------------------------------------------------------------------
// RMSNorm, in-place on bf16 columns [0,COLS) of a pitched row, 1 block/row
// ---------------------------------------------------------------------------
template <int COLS>
__global__ __launch_bounds__(256) void rmsnorm_bf_k(unsigned short* __restrict__ x,
                                                    const float* __restrict__ w,
                                                    int pitch) {
  const int row = blockIdx.x;
  unsigned short* p = x + (size_t)row * pitch;
  float ss = 0.f;
  for (int c = threadIdx.x * 8; c < COLS; c += 2048) {
    s16x8 v = *(const s16x8*)&p[c];
    #pragma unroll
    for (int j = 0; j < 8; ++j) { const float f = bf2f((unsigned short)v[j]); ss += f * f; }
  }
  #pragma unroll
  for (int off = 1; off < 64; off <<= 1) ss += __shfl_xor(ss, off, 64);
  __shared__ float sred[4];
  if ((threadIdx.x & 63) == 0) sred[threadIdx.x >> 6] = ss;
  __syncthreads();
  const float inv = rsqrtf((sred[0] + sred[1] + sred[2] + sred[3]) / (float)COLS + 1e-6f);
  for (int c = threadIdx.x * 8; c < COLS; c += 2048) {
    s16x8 v = *(const s16x8*)&p[c];
    s16x8 o;
    #pragma unroll
    for (int j = 0; j < 8; ++j)
      o[j] = (short)f2bf(bf2f((unsigned short)v[j]) * inv * w[c + j]);
    *(s16x8*)&p[c] = o;
  }
}

// ---------------------------------------------------------------------------
// GEMM: C[M,N] = A[M,K](bf16, row pitch lda) * B[N,K]^T(bf16, pitch K).
// 256x256 tile, BK=64.  512 thr = 8 waves (2M x 4N), 128x64 out per wave.
// Counted vmcnt(8) double-buffer; 4 quadrant phases with setprio (m201).
// LDS swizzle via pre-swizzled gll16 SOURCE (linear dest), XOR (row&7)<<3.
// MODE: 0 = bf16 linear, 1 = f32 linear,
//       2 = Qa layout   (row=token, col=h*192+d  -> Qa[bh][s][192])
//       3 = kv split    (col=h*256+c: c<128 -> Ka[bh][s][192];
//                        c>=128 -> V^T global [bh][dv][s], 8B packed stores)
// ---------------------------------------------------------------------------
template <int MODE>
__global__ __launch_bounds__(512, 2) void gemm256_bt(const unsigned short* __restrict__ A,
                                                     int lda,
                                                     const unsigned short* __restrict__ B,
                                                     void* __restrict__ Cout,
                                                     void* __restrict__ Cout2,
                                                     int M, int N, int K) {
  __shared__ unsigned short As[2][256 * 64];    // 64 KB
  __shared__ unsigned short Bs[2][256 * 64];    // 64 KB
  const int tid = threadIdx.x;
  const int wv = tid >> 6, l = tid & 63;
  const int lo = l & 15, hi = l >> 4;
  const int wm = wv >> 2, wn = wv & 3;          // wave grid 2 x 4
  // bijective XCD swizzle (m204)
  const int nbx = N >> 8;
  const int nwg = (M >> 8) * nbx;
  const int orig = blockIdx.x;
  const int q8 = nwg >> 3, r8 = nwg & 7, xc = orig & 7, o8 = orig >> 3;
  const int wg = (xc < r8 ? xc * (q8 + 1) : r8 * (q8 + 1) + (xc - r8) * q8) + o8;
  const int bx = wg % nbx, by = wg / nbx;
  const int m0 = by * 256, n0 = bx * 256;
  const int lrow = l >> 3;                       // row within 8-row gll16 group
  const int lcol = (((l & 7) ^ lrow) << 3);      // pre-swizzled source col (elems)

  f32x4 acc[8][4] = {};
  const int NKT = K >> 6;

  auto stage = [&](int bi, int kt) {
    #pragma unroll
    for (int i = 0; i < 4; ++i) {               // A: rows [wv*32, wv*32+32)
      const int r0 = wv * 32 + i * 8;
      gll16(A + (size_t)(m0 + r0 + lrow) * lda + kt + lcol, (void*)&As[bi][r0 * 64]);
    }
    #pragma unroll
    for (int i = 0; i < 4; ++i) {               // B: rows [wv*32, wv*32+32)
      const int r0 = wv * 32 + i * 8;
      gll16(B + (size_t)(n0 + r0 + lrow) * K + kt + lcol, (void*)&Bs[bi][r0 * 64]);
    }
  };

  stage(0, 0);

  for (int t = 0; t < NKT; ++t) {
    const int bi = t & 1;
    if (t + 1 < NKT) stage(bi ^ 1, (t + 1) * 64);
    __builtin_amdgcn_sched_barrier(0);
    if (t + 1 < NKT) asm volatile("s_waitcnt vmcnt(8)" ::: "memory");
    else             asm volatile("s_waitcnt vmcnt(0)" ::: "memory");
    __builtin_amdgcn_s_barrier();
    __builtin_amdgcn_sched_barrier(0);

    const unsigned short* Ab = As[bi];
    const unsigned short* Bb = Bs[bi];
    auto rdA = [&](int m, int kk) -> s16x8 {
      const int row = wm * 128 + m * 16 + lo;
      return *(const s16x8*)&Ab[row * 64 + ((kk * 32 + hi * 8) ^ ((row & 7) << 3))];
    };
    auto rdB = [&](int n, int kk) -> s16x8 {
      const int row = wn * 64 + n * 16 + lo;
      return *(const s16x8*)&Bb[row * 64 + ((kk * 32 + hi * 8) ^ ((row & 7) << 3))];
    };

    s16x8 a[4][2], b0[2][2], b2[2][2];
    // ---- phase 1: A rows 0-3 + B cols 0-1, quadrant (0,0)
    #pragma unroll
    for (int m = 0; m < 4; ++m) { a[m][0] = rdA(m, 0); a[m][1] = rdA(m, 1); }
    #pragma unroll
    for (int n = 0; n < 2; ++n) { b0[n][0] = rdB(n, 0); b0[n][1] = rdB(n, 1); }
    __builtin_amdgcn_sched_barrier(0);
    __builtin_amdgcn_s_setprio(1);
    #pragma unroll
    for (int m = 0; m < 4; ++m)
      #pragma unroll
      for (int n = 0; n < 2; ++n) {
        acc[m][n] = mfma_bf16(a[m][0], b0[n][0], acc[m][n]);
        acc[m][n] = mfma_bf16(a[m][1], b0[n][1], acc[m][n]);
      }
    __builtin_amdgcn_s_setprio(0);
    __builtin_amdgcn_sched_barrier(0);
    __builtin_amdgcn_s_barrier();
    // ---- phase 2: B cols 2-3 new, quadrant (0,1)
    #pragma unroll
    for (int n = 0; n < 2; ++n) { b2[n][0] = rdB(n + 2, 0); b2[n][1] = rdB(n + 2, 1); }
    __builtin_amdgcn_sched_barrier(0);
    __builtin_amdgcn_s_setprio(1);
    #pragma unroll
    for (int m = 0; m < 4; ++m)
      #pragma unroll
      for (int n = 0; n < 2; ++n) {
        acc[m][n + 2] = mfma_bf16(a[m][0], b2[n][0], acc[m][n + 2]);
        acc[m][n + 2] = mfma_bf16(a[m][1], b2[n][1], acc[m][n + 2]);
      }
    __builtin_amdgcn_s_setprio(0);
    __builtin_amdgcn_sched_barrier(0);
    __builtin_amdgcn_s_barrier();
    // ---- phase 3: A rows 4-7 new, quadrant (1,1)
    #pragma unroll
    for (int m = 0; m < 4; ++m) { a[m][0] = rdA(m + 4, 0); a[m][1] = rdA(m + 4, 1); }
    __builtin_amdgcn_sched_barrier(0);
    __builtin_amdgcn_s_setprio(1);
    #pragma unroll
    for (int m = 0; m < 4; ++m)
      #pragma unroll
      for (int n = 0; n < 2; ++n) {
        acc[m + 4][n + 2] = mfma_bf16(a[m][0], b2[n][0], acc[m + 4][n + 2]);
        acc[m + 4][n + 2] = mfma_bf16(a[m][1], b2[n][1], acc[m + 4][n + 2]);
      }
    __builtin_amdgcn_s_setprio(0);
    __builtin_amdgcn_sched_barrier(0);
    __builtin_amdgcn_s_barrier();
    // ---- phase 4: all-reuse, quadrant (1,0); end barrier = WAR guard
    __builtin_amdgcn_s_setprio(1);
    #pragma unroll
    for (int m = 0; m < 4; ++m)
      #pragma unroll
      for (int n = 0; n < 2; ++n) {
        acc[m + 4][n] = mfma_bf16(a[m][0], b0[n][0], acc[m + 4][n]);
        acc[m + 4][n] = mfma_bf16(a[m][1], b0[n][1], acc[m + 4][n]);
      }
    __builtin_amdgcn_s_setprio(0);
    __builtin_amdgcn_sched_barrier(0);
    __builtin_amdgcn_s_barrier();
  }

  if (MODE == 3) {
    // k_nope -> Ka[bh][s][192] cols 0..127; V -> V^T global [bh][dv][s] (8B packed)
    #pragma unroll
    for (int m = 0; m < 8; ++m)
      #pragma unroll
      for (int n = 0; n < 4; ++n) {
        const int row0 = m0 + wm * 128 + m * 16 + hi * 4;
        const int col = n0 + wn * 64 + n * 16 + lo;
        const int hh = col >> 8, cc = col & 255;
        const int bb = row0 >> 11, ss = row0 & 2047;
        if (cc < 128) {
          #pragma unroll
          for (int r = 0; r < 4; ++r)
            ((unsigned short*)Cout)[((size_t)((bb * Hc + hh) * Sc + ss + r)) * DQK + cc] =
                f2bf(acc[m][n][r]);
        } else {
          u16x4 o;
          #pragma unroll
          for (int r = 0; r < 4; ++r) o[r] = f2bf(acc[m][n][r]);
          *(u16x4*)&((unsigned short*)Cout2)[((size_t)((bb * Hc + hh) * DVc + (cc - 128))) * Sc + ss] = o;
        }
      }
  } else {
    #pragma unroll
    for (int m = 0; m < 8; ++m)
      #pragma unroll
      for (int n = 0; n < 4; ++n)
        #pragma unroll
        for (int r = 0; r < 4; ++r) {
          const int row = m0 + wm * 128 + m * 16 + hi * 4 + r;   // token for MODE 2
          const int col = n0 + wn * 64 + n * 16 + lo;
          const float v = acc[m][n][r];
          if (MODE == 1) {
            ((float*)Cout)[(size_t)row * N + col] = v;
          } else if (MODE == 0) {
            ((unsigned short*)Cout)[(size_t)row * N + col] = f2bf(v);
          } else {  // MODE 2
            const int hh = col / DQK, dd = col % DQK;
            const int bb = row >> 11, ss = row & 2047;
            ((unsigned short*)Cout)[((size_t)((bb * Hc + hh) * Sc + ss)) * DQK + dd] = f2bf(v);
          }
        }
  }
}

// ---------------------------------------------------------------------------
// RoPE, rope-dims only.  Each thread owns an 8-wide (j, j+32) PAIR.
// ---------------------------------------------------------------------------
DEV void rope_pair8(float pos, int j0, const s16x8& x1, const s16x8& x2,
                    s16x8& o1, s16x8& o2) {
  #pragma unroll
  for (int j = 0; j < 8; ++j) {
    const int jj = j0 + j;                       // 0..31
    const float inv = exp2f(-(float)jj * 0.4152410118f);  // 10000^(-jj/32)
    float sn, cs;
    sincosf(pos * inv, &sn, &cs);
    const float a = bf2f((unsigned short)x1[j]);
    const float c = bf2f((unsigned short)x2[j]);
    o1[j] = f2bf(a * cs - c * sn);
    o2[j] = f2bf(c * cs + a * sn);
  }
}

__global__ __launch_bounds__(256) void rope_q_k(unsigned short* __restrict__ Qa,
                                                const int* __restrict__ pos) {
  const int gid = blockIdx.x * 256 + threadIdx.x;   // Bc*Hc*Sc*4
  const int pr = gid & 3, rowp = gid >> 2;          // rowp = bh*2048+s
  const int j0 = pr * 8;
  const int bh = rowp >> 11, s = rowp & 2047;
  const int token = (bh >> 5) * Sc + s;
  unsigned short* base = Qa + (size_t)rowp * DQK + 128;
  s16x8 x1 = *(const s16x8*)&base[j0];
  s16x8 x2 = *(const s16x8*)&base[j0 + 32];
  s16x8 o1, o2;
  rope_pair8((float)pos[token], j0, x1, x2, o1, o2);
  *(s16x8*)&base[j0] = o1;
  *(s16x8*)&base[j0 + 32] = o2;
}

__global__ __launch_bounds__(256) void rope_k2_k(const unsigned short* __restrict__ kr,
                                                 const int* __restrict__ pos,
                                                 unsigned short* __restrict__ Ka) {
  const int gid = blockIdx.x * 256 + threadIdx.x;
  const int pr = gid & 3, rowp = gid >> 2;
  const int j0 = pr * 8;
  const int bh = rowp >> 11, s = rowp & 2047;
  const int h = bh & 31;
  const int token = (bh >> 5) * Sc + s;
  const unsigned short* src = kr + (size_t)token * HIDc + h * DRc;   // pitch HIDc
  s16x8 x1 = *(const s16x8*)&src[j0];
  s16x8 x2 = *(const s16x8*)&src[j0 + 32];
  s16x8 o1, o2;
  rope_pair8((float)pos[token], j0, x1, x2, o1, o2);
  unsigned short* dst = Ka + (size_t)rowp * DQK + 128;
  *(s16x8*)&dst[j0] = o1;
  *(s16x8*)&dst[j0 + 32] = o2;
}

// ---------------------------------------------------------------------------
// Flash attention, swapped-QK^T in-register softmax, 16 q-rows/wave.
// 8 waves = 128 q-rows/block.  LDS 56 KB (Ks 24K + Vs 16K + Ps 16K), all
// single-buffered, K and V both staged by gll16 (pre-swizzled source).
// __launch_bounds__(512,4): arch state ~60 VGPR + 32 AGPR -> 2 blocks/CU;
// independent blocks overlap each other's staging drains (m114).
// ---------------------------------------------------------------------------
__global__ __launch_bounds__(512, 4) void attn_k(const unsigned short* __restrict__ Q,
                                                 const unsigned short* __restrict__ Kt,
                                                 const unsigned short* __restrict__ Vt,
                                                 unsigned short* __restrict__ O) {
  __shared__ unsigned short Ks[64 * 192];       // 24 KB, swizzled rows
  __shared__ unsigned short Vs[128 * 64];       // 16 KB, V^T [dv][key] swizzled
  __shared__ unsigned short Ps[8][16 * 64];     // 16 KB, per-wave P, pitch 64
  const int bh = blockIdx.x, qblk = blockIdx.y; // bh fastest: same-bh -> same XCD
  const int b = bh >> 5, h = bh & 31;
  const int tid = threadIdx.x, w = tid >> 6, l = tid & 63;
  const int lo = l & 15, hi = l >> 4;
  const int sw = (lo & 7) << 3;                 // Ps row swizzle (row = lo)
  const unsigned short* Qb = Q + (size_t)bh * Sc * DQK;
  const unsigned short* Kb = Kt + (size_t)bh * Sc * DQK;
  const unsigned short* Vb = Vt + (size_t)bh * DVc * Sc;   // V^T [dv][s]
  const int qrow0 = qblk * 128 + w * 16;
  const float c2 = 0.10411759f;                 // (1/sqrt(192)) * log2(e)

  s16x8 qfr[6];                                 // B-frag: q=qrow0+lo, d=dc*32+hi*8
  #pragma unroll
  for (int dc = 0; dc < 6; ++dc)
    qfr[dc] = *(const s16x8*)&Qb[(size_t)(qrow0 + lo) * DQK + dc * 32 + hi * 8];

  f32x4 oacc[8] = {};
  float mrow = -INFINITY;                       // per-lane, q = qrow0+lo (log2 domain)
  float lrow = 0.f;

  auto stageK = [&](int kt) {
    #pragma unroll
    for (int i = 0; i < 3; ++i) {
      const int o = (w * 3 + i) * 1024 + l * 16;   // byte offset in 64x192 tile
      const int rr = o / 384, cc = o % 384;
      const int scc = cc ^ ((rr & 7) << 4);
      gll16(Kb + (size_t)(kt + rr) * DQK + (scc >> 1), (void*)&Ks[(w * 3 + i) * 512]);
    }
  };
  auto stageV = [&](int kt) {
    #pragma unroll
    for (int i = 0; i < 2; ++i) {
      const int dvb = w * 16 + i * 8;              // this call covers dv [dvb, dvb+8)
      const int dv = dvb + (l >> 3);
      const int ksrc = ((l & 7) ^ (dv & 7)) * 8;   // pre-swizzled source key chunk
      gll16(Vb + (size_t)dv * Sc + kt + ksrc, (void*)&Vs[dvb * 64]);
    }
  };

  constexpr int NT = Sc / 64;   // 32

  for (int t = 0; t < NT; ++t) {
    stageK(t * 64);
    stageV(t * 64);
    asm volatile("s_waitcnt vmcnt(0)" ::: "memory");
    __builtin_amdgcn_s_barrier();                // K/V tile ready
    __builtin_amdgcn_sched_barrier(0);

    // ---- QK^T swapped: sc[cf] = S[key=cf*16+hi*4+r][q=qrow0+lo]
    f32x4 sc[4] = {};
    #pragma unroll
    for (int cf = 0; cf < 4; ++cf) {
      const int krow = cf * 16 + lo;
      #pragma unroll
      for (int dc = 0; dc < 6; ++dc) {
        s16x8 kf = *(const s16x8*)&Ks[(krow * 192 + dc * 32 + hi * 8) ^ ((krow & 7) << 3)];
        sc[cf] = mfma_bf16(kf, qfr[dc], sc[cf]);
      }
    }

    // ---- in-register online softmax (defer-max, T13)
    {
      float mx = sc[0][0];
      #pragma unroll
      for (int cf = 0; cf < 4; ++cf)
        #pragma unroll
        for (int r = 0; r < 4; ++r) mx = fmaxf(mx, sc[cf][r]);
      mx = fmaxf(mx, __shfl_xor(mx, 16, 64));
      mx = fmaxf(mx, __shfl_xor(mx, 32, 64));
      const float mxl = mx * c2;
      if (!__all(mxl - mrow <= 8.f)) {           // rescale only on real growth
        const float nm = fmaxf(mrow, mxl);
        const float alpha = exp2f(mrow - nm);
        mrow = nm;
        lrow *= alpha;
        #pragma unroll
        for (int r = 0; r < 4; ++r) {
          const float ar = __shfl(alpha, hi * 4 + r, 64);
          #pragma unroll
          for (int dvf = 0; dvf < 8; ++dvf) oacc[dvf][r] *= ar;
        }
      }
      float psum = 0.f;
      #pragma unroll
      for (int cf = 0; cf < 4; ++cf) {
        sc[cf][0] = exp2f(fmaf(sc[cf][0], c2, -mrow));
        sc[cf][1] = exp2f(fmaf(sc[cf][1], c2, -mrow));
        sc[cf][2] = exp2f(fmaf(sc[cf][2], c2, -mrow));
        sc[cf][3] = exp2f(fmaf(sc[cf][3], c2, -mrow));
        psum += (sc[cf][0] + sc[cf][1]) + (sc[cf][2] + sc[cf][3]);
        const int ka = cf * 16 + hi * 4;
        *(unsigned*)&Ps[w][lo * 64 + ((ka + 0) ^ sw)] = cvt_pk_bf16(sc[cf][0], sc[cf][1]);
        *(unsigned*)&Ps[w][lo * 64 + ((ka + 2) ^ sw)] = cvt_pk_bf16(sc[cf][2], sc[cf][3]);
      }
      psum += __shfl_xor(psum, 16, 64);
      psum += __shfl_xor(psum, 32, 64);
      lrow += psum;
    }

    // ---- PV: pa from Ps (A-frag rows = q), vb = V^T from Vs
    #pragma unroll
    for (int hf = 0; hf < 2; ++hf) {
      s16x8 pa = *(const s16x8*)&Ps[w][lo * 64 + ((hf * 32 + hi * 8) ^ sw)];
      #pragma unroll
      for (int dvf = 0; dvf < 8; ++dvf) {
        const int dv = dvf * 16 + lo;
        s16x8 vb = *(const s16x8*)&Vs[dv * 64 + ((hf * 32 + hi * 8) ^ ((dv & 7) << 3))];
        oacc[dvf] = mfma_bf16(pa, vb, oacc[dvf]);
      }
    }

    __builtin_amdgcn_s_barrier();                // all reads done -> next stage safe
    __builtin_amdgcn_sched_barrier(0);
  }

  // ---- epilogue: O[token][h*128+dv] = oacc / l  (gather l across lanes)
  #pragma unroll
  for (int r = 0; r < 4; ++r) {
    const float linv = 1.f / __shfl(lrow, hi * 4 + r, 64);
    const int q = qrow0 + hi * 4 + r;
    #pragma unroll
    for (int dvf = 0; dvf < 8; ++dvf)
      O[(size_t)(b * Sc + q) * (Hc * DVc) + h * DVc + dvf * 16 + lo] =
          f2bf(oacc[dvf][r] * linv);
  }
}

// ---------------------------------------------------------------------------
extern "C" void kernel_launch(void* const* d_in, const int* in_sizes, int n_in,
                              void* d_out, int out_size, void* d_ws, size_t ws_size,
                              hipStream_t stream) {
  const float* hs      = (const float*)d_in[0];
  const int*   posids  = (const int*)d_in[1];
  const float* qa_w    = (const float*)d_in[2];
  const float* qa_ln   = (const float*)d_in[3];
  const float* qb_w    = (const float*)d_in[4];
  const float* kva_w   = (const float*)d_in[5];
  const float* kva_ln  = (const float*)d_in[6];
  const float* kvb_w   = (const float*)d_in[7];
  const float* kr_w    = (const float*)d_in[8];
  const float* o_w     = (const float*)d_in[9];
  float* out = (float*)d_out;

  // ---- overlaid workspace (total 236,978,176 B = 237.0 MB, same as proven) ----
  char* ws = (char*)d_ws;
  const size_t offF = 0;                    // 33,554,432: hs_bf -> w_qb -> w_kvb -> attn_o
  const size_t offR = offF + 33554432;      // 35,651,584: cbuf (33.5M used)
  const size_t offD = offR + 35651584;      // 50,331,648: Ka
  const size_t offA = offD + 50331648;      // 67,108,864: kv_vt (33.5M used)
  const size_t offB = offA + 67108864;      // 50,331,648: cw -> Qa -> w_o

  unsigned short* hs_bf  = (unsigned short*)(ws + offF);
  unsigned short* w_qb   = (unsigned short*)(ws + offF);   // after fused gemm
  unsigned short* w_kvb  = (unsigned short*)(ws + offF);   // after q_b gemm
  unsigned short* attn_o = (unsigned short*)(ws + offF);   // after kv_b gemm (pre-attn)
  unsigned short* cbuf   = (unsigned short*)(ws + offR);   // [qa_n | kva_n | kr], pitch 4096
  unsigned short* Ka     = (unsigned short*)(ws + offD);   // direct from kv_b + rope_k2
  unsigned short* kv_vt  = (unsigned short*)(ws + offA);   // V^T [bh][dv][s]
  unsigned short* cw     = (unsigned short*)(ws + offB);   // fused weights [4096][4096]
  unsigned short* Qa     = (unsigned short*)(ws + offB);   // direct from q_b gemm
  unsigned short* w_o    = (unsigned short*)(ws + offB);   // after attn

  auto cast = [&](const float* src, unsigned short* dst, long n) {
    cast_k<<<dim3((unsigned)((n / 4 + 255) / 256)), dim3(256), 0, stream>>>(src, dst, n);
  };

  // 1. hidden states -> bf16
  cast(hs, hs_bf, (long)Tc * HIDc);

  // 2. fused a-projection weights: [qa(1536) | kva(512) | kr(2048)] x 4096
  cast(qa_w,  cw,                              (long)QRc * HIDc);
  cast(kva_w, cw + (size_t)QRc * HIDc,         (long)KVRc * HIDc);
  cast(kr_w,  cw + (size_t)(QRc + KVRc) * HIDc,(long)Hc * DRc * HIDc);

  // 3. fused a-projection GEMM: cbuf[4096][4096] = hs_bf x cw^T  (256 blocks)
  gemm256_bt<0><<<dim3(16 * 16), dim3(512), 0, stream>>>(hs_bf, HIDc, cw,
                                                         (void*)cbuf, nullptr,
                                                         Tc, HIDc, HIDc);

  // 4. RMSNorms in place on pitched columns
  rmsnorm_bf_k<QRc><<<dim3(Tc), dim3(256), 0, stream>>>(cbuf, qa_ln, HIDc);
  rmsnorm_bf_k<KVRc><<<dim3(Tc), dim3(256), 0, stream>>>(cbuf + QRc, kva_ln, HIDc);

  // 5. q_b proj -> Qa layout directly (overwrites cw; cw dead after step 3)
  cast(qb_w, w_qb, (long)Hc * DQK * QRc);
  gemm256_bt<2><<<dim3(16 * 24), dim3(512), 0, stream>>>(cbuf, HIDc, w_qb,
                                                         (void*)Qa, nullptr,
                                                         Tc, Hc * DQK, QRc);

  // 6. kv_b proj -> k_nope into Ka, V^T into kv_vt [bh][dv][s]
  cast(kvb_w, w_kvb, (long)Hc * 256 * KVRc);
  gemm256_bt<3><<<dim3(16 * 32), dim3(512), 0, stream>>>(cbuf + QRc, HIDc, w_kvb,
                                                         (void*)Ka, (void*)kv_vt,
                                                         Tc, Hc * 256, KVRc);

  // 7. RoPE on rope dims only (pairs, race-free); Qa in-place, Ka from cbuf kr
  const int npair = Bc * Hc * Sc * 4;   // 524,288
  rope_q_k<<<dim3(npair / 256), dim3(256), 0, stream>>>(Qa, posids);
  rope_k2_k<<<dim3(npair / 256), dim3(256), 0, stream>>>(cbuf + QRc + KVRc, posids, Ka);

  // 8. attention: 128 q-rows/block, grid (64 bh, 16 qblk); bh fastest for XCD/L2
  attn_k<<<dim3(Bc * Hc, Sc / 128), dim3(512), 0, stream>>>(Qa, Ka, kv_vt, attn_o);

  // 9. output projection -> fp32 d_out (w_o cast into Qa region, dead after attn)
  cast(o_w, w_o, (long)HIDc * Hc * DVc);
  gemm256_bt<1><<<dim3(16 * 16), dim3(512), 0, stream>>>(attn_o, Hc * DVc, w_o,
                                                         (void*)out, nullptr,
                                                         Tc, HIDc, Hc * DVc);

  (void)in_sizes; (void)n_in; (void)out_size; (void)ws_size;
}